// Round 1
// baseline (3595.848 us; speedup 1.0000x reference)
//
#include <hip/hip_runtime.h>
#include <math.h>

// CrossAttentionBlock on MI355X — round 1: correct f32 baseline.
// Pipeline: im2col(img) / im2col+maxpool(ctx) -> patch GEMM x2 -> qkv GEMM
// (epilogue scatters Q/K/V per the reshape quirk) -> QK^T*scale -> softmax
// (in d_out attn region) -> PV (scatter to O2 via inverse quirk) -> proj GEMM
// -> fused 1x1conv + bilinear x2 (align_corners) + sigmoid + gate.
//
// Workspace layout (floats), peak 62,914,560 floats = 252 MB:
//   [0        .. 6291456)  Aimg   (8192x768)      -> later reused as O2 (with Actx)
//   [6291456  .. 12582912) Actx   (8192x768)
//   [12582912 .. 25165824) XC     (8x2048x768)    -> later reused as P
//   [25165824 .. 37748736) Qm     (8x8x1024x192)
//   [37748736 .. 50331648) Km
//   [50331648 .. 62914560) Vm

namespace {

constexpr float SCALE = 0.10206207261596577f;  // 96^-0.5 (reference quirk)

struct Smem { float As[16][65]; float Bs[16][65]; };

// Generic 64x64 tile, 16x16 threads, 4x4 per thread, K-chunk 16.
// A is row-major [M][K]. B: BT=true -> [Ncols][K] (k-contiguous, "B^T");
// BT=false -> [K][Ncols].
template <bool BT>
__device__ __forceinline__ void gemm_tile(const float* __restrict__ A, int lda,
                                          const float* __restrict__ Bm, int ldb,
                                          int m0, int n0, int Kdim,
                                          Smem& sm, float acc[4][4]) {
  const int tid = threadIdx.y * 16 + threadIdx.x;
  for (int kc = 0; kc < Kdim; kc += 16) {
#pragma unroll
    for (int i = 0; i < 4; ++i) {
      int fl = tid + i * 256;
      int m = fl >> 4, k = fl & 15;
      sm.As[k][m] = A[(size_t)(m0 + m) * lda + kc + k];
    }
    if (BT) {
#pragma unroll
      for (int i = 0; i < 4; ++i) {
        int fl = tid + i * 256;
        int n = fl >> 4, k = fl & 15;
        sm.Bs[k][n] = Bm[(size_t)(n0 + n) * ldb + kc + k];
      }
    } else {
#pragma unroll
      for (int i = 0; i < 4; ++i) {
        int fl = tid + i * 256;
        int n = fl & 63, k = fl >> 6;
        sm.Bs[k][n] = Bm[(size_t)(kc + k) * ldb + n0 + n];
      }
    }
    __syncthreads();
#pragma unroll
    for (int kk = 0; kk < 16; ++kk) {
      float a[4], b[4];
#pragma unroll
      for (int i = 0; i < 4; ++i) a[i] = sm.As[kk][threadIdx.y * 4 + i];
#pragma unroll
      for (int j = 0; j < 4; ++j) b[j] = sm.Bs[kk][threadIdx.x * 4 + j];
#pragma unroll
      for (int i = 0; i < 4; ++i)
#pragma unroll
        for (int j = 0; j < 4; ++j) acc[i][j] = fmaf(a[i], b[j], acc[i][j]);
    }
    __syncthreads();
  }
}

// ---- im2col ---------------------------------------------------------------

__global__ void im2col_img(const float* __restrict__ img, float* __restrict__ A) {
  const int t = threadIdx.x;    // 0..191
  const int row = blockIdx.x;   // 0..8191  (b*1024 + n)
  const int k4 = t * 4;         // col = c*256 + i*16 + j
  const int c = k4 >> 8;
  const int rem = k4 & 255;
  const int i = rem >> 4;
  const int j = rem & 15;
  const int b = row >> 10, n = row & 1023;
  const int hp = n >> 5, wp = n & 31;
  const float4 v = *(const float4*)(img + ((size_t)(b * 3 + c) * 512 + hp * 16 + i) * 512 + wp * 16 + j);
  *(float4*)(A + (size_t)row * 768 + k4) = v;
}

// ctx branch: 2x2 maxpool fused into the gather (pooled tensor never stored)
__global__ void im2col_ctx(const float* __restrict__ ctx, float* __restrict__ A) {
  const int t = threadIdx.x;
  const int row = blockIdx.x;
  const int k4 = t * 4;
  const int c = k4 >> 8;
  const int rem = k4 & 255;
  const int i = rem >> 4;
  const int j = rem & 15;
  const int b = row >> 10, n = row & 1023;
  const int hp = n >> 5, wp = n & 31;
  const int y = hp * 16 + i;        // pooled coords
  const int x = wp * 16 + j;        // x..x+3
  const float* base = ctx + ((size_t)(b * 3 + c) * 1024 + 2 * y) * 1024 + 2 * x;
  const float4 r0a = *(const float4*)(base);
  const float4 r0b = *(const float4*)(base + 4);
  const float4 r1a = *(const float4*)(base + 1024);
  const float4 r1b = *(const float4*)(base + 1028);
  float4 o;
  o.x = fmaxf(fmaxf(r0a.x, r0a.y), fmaxf(r1a.x, r1a.y));
  o.y = fmaxf(fmaxf(r0a.z, r0a.w), fmaxf(r1a.z, r1a.w));
  o.z = fmaxf(fmaxf(r0b.x, r0b.y), fmaxf(r1b.x, r1b.y));
  o.w = fmaxf(fmaxf(r0b.z, r0b.w), fmaxf(r1b.z, r1b.w));
  *(float4*)(A + (size_t)row * 768 + k4) = o;
}

// ---- patch embed GEMM -----------------------------------------------------
// XC[b][branch*1024+n][col] = A[b*1024+n] . W[col] + bias[col] + pos[n][col]
__global__ __launch_bounds__(256) void patch_gemm(
    const float* __restrict__ A, const float* __restrict__ Wt,
    const float* __restrict__ bias, const float* __restrict__ pos,
    float* __restrict__ XC, int branch) {
  __shared__ Smem sm;
  float acc[4][4] = {{0.f}};
  const int m0 = blockIdx.y * 64, n0 = blockIdx.x * 64;
  gemm_tile<true>(A, 768, Wt, 768, m0, n0, 768, sm, acc);
#pragma unroll
  for (int i = 0; i < 4; ++i) {
    const int row = m0 + threadIdx.y * 4 + i;
    const int b = row >> 10, n = row & 1023;
    float* dst = XC + ((size_t)b * 2048 + branch * 1024 + n) * 768;
#pragma unroll
    for (int j = 0; j < 4; ++j) {
      const int col = n0 + threadIdx.x * 4 + j;
      dst[col] = acc[i][j] + bias[col] + pos[(size_t)n * 768 + col];
    }
  }
}

// ---- qkv GEMM with Q/K/V scatter epilogue ---------------------------------
// row r (within batch): n = r>>1, odd = r&1.
//  odd=0: col<1536 -> Q[h=col/192]; col>=1536 -> K[h=(col-1536)/192] (h 0..3)
//  odd=1: col<768  -> K[h=4+col/192];  col>=768 -> V[h=(col-768)/192]
__global__ __launch_bounds__(256) void qkv_gemm(
    const float* __restrict__ XC, const float* __restrict__ Wq,
    float* __restrict__ Qm, float* __restrict__ Km, float* __restrict__ Vm) {
  __shared__ Smem sm;
  float acc[4][4] = {{0.f}};
  const int m0 = blockIdx.y * 64, n0 = blockIdx.x * 64;
  gemm_tile<false>(XC, 768, Wq, 2304, m0, n0, 768, sm, acc);
#pragma unroll
  for (int i = 0; i < 4; ++i) {
    const int row = m0 + threadIdx.y * 4 + i;
    const int b = row >> 11, rl = row & 2047;
    const int n = rl >> 1, odd = rl & 1;
#pragma unroll
    for (int j = 0; j < 4; ++j) {
      const int col = n0 + threadIdx.x * 4 + j;
      const float v = acc[i][j];
      int h, d;
      float* dst;
      if (!odd) {
        if (col < 1536) { h = col / 192; d = col - h * 192; dst = Qm; }
        else { const int c2 = col - 1536; h = c2 / 192; d = c2 - h * 192; dst = Km; }
      } else {
        if (col < 768) { h = 4 + col / 192; d = col - (col / 192) * 192; dst = Km; }
        else { const int c2 = col - 768; h = c2 / 192; d = c2 - h * 192; dst = Vm; }
      }
      dst[((size_t)(b * 8 + h) * 1024 + n) * 192 + d] = v;
    }
  }
}

// ---- QK^T * scale ---------------------------------------------------------
__global__ __launch_bounds__(256) void qk_gemm(
    const float* __restrict__ Qm, const float* __restrict__ Km,
    float* __restrict__ S) {
  __shared__ Smem sm;
  float acc[4][4] = {{0.f}};
  const int bh = blockIdx.z;
  const int n0 = blockIdx.y * 64;  // query rows
  const int m0 = blockIdx.x * 64;  // key cols
  const float* Q = Qm + (size_t)bh * 1024 * 192;
  const float* K = Km + (size_t)bh * 1024 * 192;
  gemm_tile<true>(Q, 192, K, 192, n0, m0, 192, sm, acc);
  float* Sb = S + (size_t)bh * 1024 * 1024;
#pragma unroll
  for (int i = 0; i < 4; ++i) {
    const int r = n0 + threadIdx.y * 4 + i;
#pragma unroll
    for (int j = 0; j < 4; ++j) {
      const int cc = m0 + threadIdx.x * 4 + j;
      Sb[(size_t)r * 1024 + cc] = acc[i][j] * SCALE;
    }
  }
}

// ---- row softmax over 1024, in place --------------------------------------
__global__ __launch_bounds__(256) void softmax_k(float* __restrict__ S) {
  __shared__ float red[8];
  float* p = S + (size_t)blockIdx.x * 1024;
  const int tid = threadIdx.x;
  float4 f = ((const float4*)p)[tid];
  float mx = fmaxf(fmaxf(f.x, f.y), fmaxf(f.z, f.w));
#pragma unroll
  for (int off = 32; off; off >>= 1) mx = fmaxf(mx, __shfl_xor(mx, off));
  if ((tid & 63) == 0) red[tid >> 6] = mx;
  __syncthreads();
  mx = fmaxf(fmaxf(red[0], red[1]), fmaxf(red[2], red[3]));
  const float e0 = expf(f.x - mx), e1 = expf(f.y - mx);
  const float e2 = expf(f.z - mx), e3 = expf(f.w - mx);
  float s = e0 + e1 + e2 + e3;
#pragma unroll
  for (int off = 32; off; off >>= 1) s += __shfl_xor(s, off);
  if ((tid & 63) == 0) red[4 + (tid >> 6)] = s;
  __syncthreads();
  const float inv = 1.0f / (red[4] + red[5] + red[6] + red[7]);
  ((float4*)p)[tid] = make_float4(e0 * inv, e1 * inv, e2 * inv, e3 * inv);
}

// ---- PV with inverse-quirk scatter ----------------------------------------
// O2[b][2n + (h>=4)][(h&3)*192 + d] = sum_m attn[b,h,n,m] * V[b,h,m,d]
__global__ __launch_bounds__(256) void pv_gemm(
    const float* __restrict__ S, const float* __restrict__ Vm,
    float* __restrict__ O2) {
  __shared__ Smem sm;
  float acc[4][4] = {{0.f}};
  const int bh = blockIdx.z;
  const int n0 = blockIdx.y * 64;  // query rows
  const int d0 = blockIdx.x * 64;  // head-dim cols (192 total)
  const float* A = S + (size_t)bh * 1024 * 1024;
  const float* V = Vm + (size_t)bh * 1024 * 192;
  gemm_tile<false>(A, 1024, V, 192, n0, d0, 1024, sm, acc);
  const int b = bh >> 3, h = bh & 7;
#pragma unroll
  for (int i = 0; i < 4; ++i) {
    const int n = n0 + threadIdx.y * 4 + i;
    const int r = 2 * n + (h >> 2);
#pragma unroll
    for (int j = 0; j < 4; ++j) {
      const int d = d0 + threadIdx.x * 4 + j;
      O2[((size_t)b * 2048 + r) * 768 + (h & 3) * 192 + d] = acc[i][j];
    }
  }
}

// ---- proj GEMM + bias -----------------------------------------------------
__global__ __launch_bounds__(256) void proj_gemm(
    const float* __restrict__ O2, const float* __restrict__ Wp,
    const float* __restrict__ bias, float* __restrict__ P) {
  __shared__ Smem sm;
  float acc[4][4] = {{0.f}};
  const int m0 = blockIdx.y * 64, n0 = blockIdx.x * 64;
  gemm_tile<false>(O2, 768, Wp, 384, m0, n0, 768, sm, acc);
#pragma unroll
  for (int i = 0; i < 4; ++i) {
    const int row = m0 + threadIdx.y * 4 + i;
#pragma unroll
    for (int j = 0; j < 4; ++j) {
      const int col = n0 + threadIdx.x * 4 + j;
      P[(size_t)row * 384 + col] = acc[i][j] + bias[col];
    }
  }
}

// ---- fused 1x1 conv + bilinear x2 (align_corners) + sigmoid + gate --------
// P flat per batch IS y (3,512,512). Output (8,3,1024,1024).
__global__ __launch_bounds__(256) void final_up(
    const float* __restrict__ P, const float* __restrict__ ctx,
    const float* __restrict__ up_w, const float* __restrict__ up_b,
    float* __restrict__ outY) {
  const size_t idx = (size_t)blockIdx.x * 256 + threadIdx.x;  // 8*1024*1024
  const int ow = (int)(idx & 1023);
  const int oh = (int)((idx >> 10) & 1023);
  const int b = (int)(idx >> 20);
  const float rr = 511.0f / 1023.0f;
  const float fy = oh * rr;
  const int y0 = (int)fy;
  const int y1 = y0 < 511 ? y0 + 1 : 511;
  const float wy = fy - (float)y0;
  const float fx = ow * rr;
  const int x0 = (int)fx;
  const int x1 = x0 < 511 ? x0 + 1 : 511;
  const float wx = fx - (float)x0;
  const float* Pb = P + (size_t)b * 786432;
  float v[3];
#pragma unroll
  for (int ci = 0; ci < 3; ++ci) {
    const float* pc = Pb + ci * 262144;
    const float a00 = pc[y0 * 512 + x0], a01 = pc[y0 * 512 + x1];
    const float a10 = pc[y1 * 512 + x0], a11 = pc[y1 * 512 + x1];
    v[ci] = (a00 * (1.f - wx) + a01 * wx) * (1.f - wy) +
            (a10 * (1.f - wx) + a11 * wx) * wy;
  }
#pragma unroll
  for (int co = 0; co < 3; ++co) {
    float u = up_b[co];
#pragma unroll
    for (int ci = 0; ci < 3; ++ci) u = fmaf(up_w[co * 3 + ci], v[ci], u);
    const float sg = 1.0f / (1.0f + expf(-u));
    const size_t o = (((size_t)b * 3 + co) << 20) + ((size_t)oh << 10) + ow;
    outY[o] = sg * ctx[o];
  }
}

}  // namespace

extern "C" void kernel_launch(void* const* d_in, const int* in_sizes, int n_in,
                              void* d_out, int out_size, void* d_ws, size_t ws_size,
                              hipStream_t stream) {
  const float* img = (const float*)d_in[0];
  const float* ctx = (const float*)d_in[1];
  const float* patch_w = (const float*)d_in[2];
  const float* patch_b = (const float*)d_in[3];
  const float* pos1 = (const float*)d_in[4];
  const float* ctx_w = (const float*)d_in[5];
  const float* ctx_b = (const float*)d_in[6];
  const float* pos2 = (const float*)d_in[7];
  const float* qkv_w = (const float*)d_in[8];
  const float* proj_w = (const float*)d_in[9];
  const float* proj_b = (const float*)d_in[10];
  const float* up_w = (const float*)d_in[11];
  const float* up_b = (const float*)d_in[12];

  float* ws = (float*)d_ws;
  float* Aimg = ws + 0;
  float* Actx = ws + 6291456;
  float* XC   = ws + 12582912;
  float* Qm   = ws + 25165824;
  float* Km   = ws + 37748736;
  float* Vm   = ws + 50331648;
  float* O2   = ws + 0;          // reuses Aimg+Actx (dead after qkv_gemm)
  float* P    = ws + 12582912;   // reuses XC (dead after qkv_gemm)

  float* outY = (float*)d_out;                 // (8,3,1024,1024)
  float* outA = (float*)d_out + 25165824;      // (8,8,1024,1024)

  im2col_img<<<8192, 192, 0, stream>>>(img, Aimg);
  im2col_ctx<<<8192, 192, 0, stream>>>(ctx, Actx);
  patch_gemm<<<dim3(12, 128), dim3(16, 16), 0, stream>>>(Aimg, patch_w, patch_b, pos1, XC, 0);
  patch_gemm<<<dim3(12, 128), dim3(16, 16), 0, stream>>>(Actx, ctx_w, ctx_b, pos2, XC, 1);
  qkv_gemm<<<dim3(36, 256), dim3(16, 16), 0, stream>>>(XC, qkv_w, Qm, Km, Vm);
  qk_gemm<<<dim3(16, 16, 64), dim3(16, 16), 0, stream>>>(Qm, Km, outA);
  softmax_k<<<65536, 256, 0, stream>>>(outA);
  pv_gemm<<<dim3(3, 16, 64), dim3(16, 16), 0, stream>>>(outA, Vm, O2);
  proj_gemm<<<dim3(6, 256), dim3(16, 16), 0, stream>>>(O2, proj_w, proj_b, P);
  final_up<<<32768, 256, 0, stream>>>(P, ctx, up_w, up_b, outY);
}

// Round 3
// 919.896 us; speedup vs baseline: 3.9090x; 3.9090x over previous
//
#include <hip/hip_runtime.h>
#include <math.h>

// CrossAttentionBlock on MI355X — round 2 (resubmit after broker timeout):
// bf16 MFMA for all matmuls.
// m97 structure: 128x128 tile, 4 waves (2x2), 4x4 16x16x32 frags/wave, BK=32,
// global_load_lds width-16 staging, 2 barriers/K-step.
//
// Workspace (bytes):
//   [0          ..134217728) Pbf (64x1024x1024 bf16)  — earlier aliased as:
//        [0..12582912)   Aimg bf16 [8192][768]
//        [12582912..25165824) Actx bf16
//        [25165824..50331648) XC  bf16 [16384][768]
//        [50331648..75497472) Qm  bf16 [64][1024][192]
//        [75497472..100663296) Km
//   [134217728..159383552) Vt  bf16 [64][192][1024]
//   [159383552..184549376) O2  bf16 [16384][768]
//   [184549376..209715200) P   f32  [16384][384]
//   [209715200..) weight conversions (Wpat, Wctx, Wqt, Wpt)

namespace {

typedef unsigned short u16;
typedef __attribute__((ext_vector_type(8))) __bf16 bf16x8;
typedef __attribute__((ext_vector_type(4))) float f32x4;

constexpr float SCALE = 0.10206207261596577f;  // 96^-0.5 (reference quirk)

__device__ __forceinline__ u16 f2bf(float x) {
  unsigned u = __float_as_uint(x);
  return (u16)((u + 0x7FFFu + ((u >> 16) & 1u)) >> 16);
}

// ---- generic MFMA core ----------------------------------------------------
// A bf16 [M][lda] row-major (k-contiguous); B bf16 [N][ldb] (k-contiguous).
// 256 threads = 4 waves in 2x2. acc[mi][ni]: wave tile (BM/2)x(BN/2).
template <int BM, int BN>
__device__ __forceinline__ void mfma_core(const u16* __restrict__ A, int lda, int m0,
                                          const u16* __restrict__ B, int ldb, int n0,
                                          int K, u16* As, u16* Bs,
                                          f32x4 (&acc)[BM / 32][BN / 32]) {
  const int tid = threadIdx.x;
  const int lane = tid & 63, wid = tid >> 6;
  const int wr = wid >> 1, wc = wid & 1;
  const int fr = lane & 15, ks = lane >> 4;
  const int srow = lane >> 2, sslot = lane & 3;
  for (int kc = 0; kc < K; kc += 32) {
#pragma unroll
    for (int t = 0; t < BM / 64; ++t) {
      const int rb = (wid * (BM / 64) + t) * 16;
      const u16* src = A + (size_t)(m0 + rb + srow) * lda + kc + sslot * 8;
      __builtin_amdgcn_global_load_lds((const __attribute__((address_space(1))) void*)src,
                                       (__attribute__((address_space(3))) void*)(As + rb * 32),
                                       16, 0, 0);
    }
#pragma unroll
    for (int t = 0; t < BN / 64; ++t) {
      const int rb = (wid * (BN / 64) + t) * 16;
      const u16* src = B + (size_t)(n0 + rb + srow) * ldb + kc + sslot * 8;
      __builtin_amdgcn_global_load_lds((const __attribute__((address_space(1))) void*)src,
                                       (__attribute__((address_space(3))) void*)(Bs + rb * 32),
                                       16, 0, 0);
    }
    __syncthreads();
    bf16x8 a[BM / 32], b[BN / 32];
#pragma unroll
    for (int mi = 0; mi < BM / 32; ++mi)
      a[mi] = *(const bf16x8*)(As + (wr * (BM / 2) + mi * 16 + fr) * 32 + ks * 8);
#pragma unroll
    for (int ni = 0; ni < BN / 32; ++ni)
      b[ni] = *(const bf16x8*)(Bs + (wc * (BN / 2) + ni * 16 + fr) * 32 + ks * 8);
#pragma unroll
    for (int mi = 0; mi < BM / 32; ++mi)
#pragma unroll
      for (int ni = 0; ni < BN / 32; ++ni)
        acc[mi][ni] = __builtin_amdgcn_mfma_f32_16x16x32_bf16(a[mi], b[ni], acc[mi][ni], 0, 0, 0);
    __syncthreads();
  }
}

// ---- conversions ----------------------------------------------------------

__global__ void cvt_bf16(const float* __restrict__ in, u16* __restrict__ out) {
  const int i = blockIdx.x * 256 + threadIdx.x;
  const float4 v = ((const float4*)in)[i];
  ((ushort4*)out)[i] = make_ushort4(f2bf(v.x), f2bf(v.y), f2bf(v.z), f2bf(v.w));
}

// in [K][N] f32 -> out [N][K] bf16
__global__ void cvt_t(const float* __restrict__ in, u16* __restrict__ out, int N, int K) {
  __shared__ float t[32][33];
  const int tx = threadIdx.x, ty = threadIdx.y;
  const int bn = blockIdx.x * 32, bk = blockIdx.y * 32;
#pragma unroll
  for (int i = 0; i < 4; ++i) t[ty * 4 + i][tx] = in[(size_t)(bk + ty * 4 + i) * N + bn + tx];
  __syncthreads();
#pragma unroll
  for (int i = 0; i < 4; ++i)
    out[(size_t)(bn + ty * 4 + i) * K + bk + tx] = f2bf(t[tx][ty * 4 + i]);
}

// ---- im2col (bf16 out) ----------------------------------------------------

__global__ void im2col_img(const float* __restrict__ img, u16* __restrict__ A) {
  const int t = threadIdx.x;   // 0..191
  const int row = blockIdx.x;  // b*1024 + n
  const int k4 = t * 4;
  const int c = k4 >> 8, rem = k4 & 255, i = rem >> 4, j = rem & 15;
  const int b = row >> 10, n = row & 1023;
  const int hp = n >> 5, wp = n & 31;
  const float4 v = *(const float4*)(img + ((size_t)(b * 3 + c) * 512 + hp * 16 + i) * 512 + wp * 16 + j);
  *(ushort4*)(A + (size_t)row * 768 + k4) = make_ushort4(f2bf(v.x), f2bf(v.y), f2bf(v.z), f2bf(v.w));
}

__global__ void im2col_ctx(const float* __restrict__ ctx, u16* __restrict__ A) {
  const int t = threadIdx.x;
  const int row = blockIdx.x;
  const int k4 = t * 4;
  const int c = k4 >> 8, rem = k4 & 255, i = rem >> 4, j = rem & 15;
  const int b = row >> 10, n = row & 1023;
  const int hp = n >> 5, wp = n & 31;
  const int y = hp * 16 + i, x = wp * 16 + j;
  const float* base = ctx + ((size_t)(b * 3 + c) * 1024 + 2 * y) * 1024 + 2 * x;
  const float4 r0a = *(const float4*)(base);
  const float4 r0b = *(const float4*)(base + 4);
  const float4 r1a = *(const float4*)(base + 1024);
  const float4 r1b = *(const float4*)(base + 1028);
  *(ushort4*)(A + (size_t)row * 768 + k4) = make_ushort4(
      f2bf(fmaxf(fmaxf(r0a.x, r0a.y), fmaxf(r1a.x, r1a.y))),
      f2bf(fmaxf(fmaxf(r0a.z, r0a.w), fmaxf(r1a.z, r1a.w))),
      f2bf(fmaxf(fmaxf(r0b.x, r0b.y), fmaxf(r1b.x, r1b.y))),
      f2bf(fmaxf(fmaxf(r0b.z, r0b.w), fmaxf(r1b.z, r1b.w))));
}

// ---- GEMM kernels ---------------------------------------------------------

__global__ __launch_bounds__(256) void patch_gemm(
    const u16* __restrict__ A, const u16* __restrict__ W,
    const float* __restrict__ bias, const float* __restrict__ pos,
    u16* __restrict__ XC, int branch) {
  __shared__ u16 As[128 * 32], Bs[128 * 32];
  f32x4 acc[4][4];
#pragma unroll
  for (int mi = 0; mi < 4; ++mi)
#pragma unroll
    for (int ni = 0; ni < 4; ++ni) acc[mi][ni] = f32x4{0.f, 0.f, 0.f, 0.f};
  const int m0 = blockIdx.y * 128, n0 = blockIdx.x * 128;
  mfma_core<128, 128>(A, 768, m0, W, 768, n0, 768, As, Bs, acc);
  const int tid = threadIdx.x, lane = tid & 63, wid = tid >> 6;
  const int wr = wid >> 1, wc = wid & 1, fr = lane & 15, ks = lane >> 4;
#pragma unroll
  for (int mi = 0; mi < 4; ++mi)
#pragma unroll
    for (int j = 0; j < 4; ++j) {
      const int row = m0 + wr * 64 + mi * 16 + ks * 4 + j;
      const int b = row >> 10, n = row & 1023;
      u16* dst = XC + ((size_t)b * 2048 + branch * 1024 + n) * 768;
#pragma unroll
      for (int ni = 0; ni < 4; ++ni) {
        const int col = n0 + wc * 64 + ni * 16 + fr;
        dst[col] = f2bf(acc[mi][ni][j] + bias[col] + pos[(size_t)n * 768 + col]);
      }
    }
}

__global__ __launch_bounds__(256) void qkv_gemm(
    const u16* __restrict__ XC, const u16* __restrict__ Wt,
    u16* __restrict__ Qm, u16* __restrict__ Km, u16* __restrict__ Vt) {
  __shared__ u16 As[128 * 32], Bs[128 * 32];
  f32x4 acc[4][4];
#pragma unroll
  for (int mi = 0; mi < 4; ++mi)
#pragma unroll
    for (int ni = 0; ni < 4; ++ni) acc[mi][ni] = f32x4{0.f, 0.f, 0.f, 0.f};
  const int m0 = blockIdx.y * 128, n0 = blockIdx.x * 128;
  mfma_core<128, 128>(XC, 768, m0, Wt, 768, n0, 768, As, Bs, acc);
  const int tid = threadIdx.x, lane = tid & 63, wid = tid >> 6;
  const int wr = wid >> 1, wc = wid & 1, fr = lane & 15, ks = lane >> 4;
#pragma unroll
  for (int mi = 0; mi < 4; ++mi)
#pragma unroll
    for (int j = 0; j < 4; ++j) {
      const int row = m0 + wr * 64 + mi * 16 + ks * 4 + j;
      const int b = row >> 11, rl = row & 2047;
      const int n = rl >> 1, odd = rl & 1;
#pragma unroll
      for (int ni = 0; ni < 4; ++ni) {
        const int col = n0 + wc * 64 + ni * 16 + fr;
        const u16 v = f2bf(acc[mi][ni][j]);
        if (!odd) {
          if (col < 1536) {
            const int h = col / 192, d = col - h * 192;
            Qm[((size_t)(b * 8 + h) * 1024 + n) * 192 + d] = v;
          } else {
            const int c2 = col - 1536, h = c2 / 192, d = c2 - h * 192;
            Km[((size_t)(b * 8 + h) * 1024 + n) * 192 + d] = v;
          }
        } else {
          if (col < 768) {
            const int h = col / 192, d = col - h * 192;
            Km[((size_t)(b * 8 + 4 + h) * 1024 + n) * 192 + d] = v;
          } else {
            const int c2 = col - 768, h = c2 / 192, d = c2 - h * 192;
            Vt[((size_t)(b * 8 + h) * 192 + d) * 1024 + n] = v;
          }
        }
      }
    }
}

__global__ __launch_bounds__(256) void qk_gemm(
    const u16* __restrict__ Qm, const u16* __restrict__ Km, float* __restrict__ S) {
  __shared__ u16 As[128 * 32], Bs[128 * 32];
  f32x4 acc[4][4];
#pragma unroll
  for (int mi = 0; mi < 4; ++mi)
#pragma unroll
    for (int ni = 0; ni < 4; ++ni) acc[mi][ni] = f32x4{0.f, 0.f, 0.f, 0.f};
  const int bh = blockIdx.z;
  const int m0 = blockIdx.y * 128;  // query rows
  const int n0 = blockIdx.x * 128;  // key cols
  mfma_core<128, 128>(Qm + (size_t)bh * 196608, 192, m0, Km + (size_t)bh * 196608, 192, n0, 192,
                      As, Bs, acc);
  float* Sb = S + ((size_t)bh << 20);
  const int tid = threadIdx.x, lane = tid & 63, wid = tid >> 6;
  const int wr = wid >> 1, wc = wid & 1, fr = lane & 15, ks = lane >> 4;
#pragma unroll
  for (int mi = 0; mi < 4; ++mi)
#pragma unroll
    for (int j = 0; j < 4; ++j) {
      const int r = m0 + wr * 64 + mi * 16 + ks * 4 + j;
#pragma unroll
      for (int ni = 0; ni < 4; ++ni) {
        const int cc = n0 + wc * 64 + ni * 16 + fr;
        Sb[(size_t)r * 1024 + cc] = acc[mi][ni][j] * SCALE;
      }
    }
}

// ---- softmax (f32 in d_out, + bf16 copy for PV) ---------------------------
__global__ __launch_bounds__(256) void softmax_k(float* __restrict__ S, u16* __restrict__ Pbf) {
  __shared__ float red[8];
  float* p = S + ((size_t)blockIdx.x << 10);
  const int tid = threadIdx.x;
  float4 f = ((const float4*)p)[tid];
  float mx = fmaxf(fmaxf(f.x, f.y), fmaxf(f.z, f.w));
#pragma unroll
  for (int off = 32; off; off >>= 1) mx = fmaxf(mx, __shfl_xor(mx, off));
  if ((tid & 63) == 0) red[tid >> 6] = mx;
  __syncthreads();
  mx = fmaxf(fmaxf(red[0], red[1]), fmaxf(red[2], red[3]));
  const float e0 = expf(f.x - mx), e1 = expf(f.y - mx);
  const float e2 = expf(f.z - mx), e3 = expf(f.w - mx);
  float s = e0 + e1 + e2 + e3;
#pragma unroll
  for (int off = 32; off; off >>= 1) s += __shfl_xor(s, off);
  if ((tid & 63) == 0) red[4 + (tid >> 6)] = s;
  __syncthreads();
  const float inv = 1.0f / (red[4] + red[5] + red[6] + red[7]);
  const float o0 = e0 * inv, o1 = e1 * inv, o2 = e2 * inv, o3 = e3 * inv;
  ((float4*)p)[tid] = make_float4(o0, o1, o2, o3);
  *(ushort4*)(Pbf + ((size_t)blockIdx.x << 10) + tid * 4) =
      make_ushort4(f2bf(o0), f2bf(o1), f2bf(o2), f2bf(o3));
}

// ---- PV: attn(1024x1024) x V(1024x192), B-operand Vt[192][1024] -----------
__global__ __launch_bounds__(256) void pv_gemm(
    const u16* __restrict__ Pbf, const u16* __restrict__ Vt, u16* __restrict__ O2) {
  __shared__ u16 As[128 * 32], Bs[192 * 32];
  f32x4 acc[4][6];
#pragma unroll
  for (int mi = 0; mi < 4; ++mi)
#pragma unroll
    for (int ni = 0; ni < 6; ++ni) acc[mi][ni] = f32x4{0.f, 0.f, 0.f, 0.f};
  const int bh = blockIdx.z;
  const int m0 = blockIdx.y * 128;
  mfma_core<128, 192>(Pbf + ((size_t)bh << 20), 1024, m0, Vt + (size_t)bh * 196608, 1024, 0, 1024,
                      As, Bs, acc);
  const int b = bh >> 3, h = bh & 7;
  const int tid = threadIdx.x, lane = tid & 63, wid = tid >> 6;
  const int wr = wid >> 1, wc = wid & 1, fr = lane & 15, ks = lane >> 4;
#pragma unroll
  for (int mi = 0; mi < 4; ++mi)
#pragma unroll
    for (int j = 0; j < 4; ++j) {
      const int n = m0 + wr * 64 + mi * 16 + ks * 4 + j;
      const int r = 2 * n + (h >> 2);
#pragma unroll
      for (int ni = 0; ni < 6; ++ni) {
        const int d = wc * 96 + ni * 16 + fr;
        O2[((size_t)b * 2048 + r) * 768 + (h & 3) * 192 + d] = f2bf(acc[mi][ni][j]);
      }
    }
}

__global__ __launch_bounds__(256) void proj_gemm(
    const u16* __restrict__ O2, const u16* __restrict__ Wt,
    const float* __restrict__ bias, float* __restrict__ P) {
  __shared__ u16 As[128 * 32], Bs[128 * 32];
  f32x4 acc[4][4];
#pragma unroll
  for (int mi = 0; mi < 4; ++mi)
#pragma unroll
    for (int ni = 0; ni < 4; ++ni) acc[mi][ni] = f32x4{0.f, 0.f, 0.f, 0.f};
  const int m0 = blockIdx.y * 128, n0 = blockIdx.x * 128;
  mfma_core<128, 128>(O2, 768, m0, Wt, 768, n0, 768, As, Bs, acc);
  const int tid = threadIdx.x, lane = tid & 63, wid = tid >> 6;
  const int wr = wid >> 1, wc = wid & 1, fr = lane & 15, ks = lane >> 4;
#pragma unroll
  for (int mi = 0; mi < 4; ++mi)
#pragma unroll
    for (int j = 0; j < 4; ++j) {
      const int row = m0 + wr * 64 + mi * 16 + ks * 4 + j;
#pragma unroll
      for (int ni = 0; ni < 4; ++ni) {
        const int col = n0 + wc * 64 + ni * 16 + fr;
        P[(size_t)row * 384 + col] = acc[mi][ni][j] + bias[col];
      }
    }
}

// ---- fused 1x1 conv + bilinear x2 (align_corners) + sigmoid + gate --------
__global__ __launch_bounds__(256) void final_up(
    const float* __restrict__ P, const float* __restrict__ ctx,
    const float* __restrict__ up_w, const float* __restrict__ up_b,
    float* __restrict__ outY) {
  const size_t idx = (size_t)blockIdx.x * 256 + threadIdx.x;
  const int ow = (int)(idx & 1023);
  const int oh = (int)((idx >> 10) & 1023);
  const int b = (int)(idx >> 20);
  const float rr = 511.0f / 1023.0f;
  const float fy = oh * rr;
  const int y0 = (int)fy;
  const int y1 = y0 < 511 ? y0 + 1 : 511;
  const float wy = fy - (float)y0;
  const float fx = ow * rr;
  const int x0 = (int)fx;
  const int x1 = x0 < 511 ? x0 + 1 : 511;
  const float wx = fx - (float)x0;
  const float* Pb = P + (size_t)b * 786432;
  float v[3];
#pragma unroll
  for (int ci = 0; ci < 3; ++ci) {
    const float* pc = Pb + ci * 262144;
    const float a00 = pc[y0 * 512 + x0], a01 = pc[y0 * 512 + x1];
    const float a10 = pc[y1 * 512 + x0], a11 = pc[y1 * 512 + x1];
    v[ci] = (a00 * (1.f - wx) + a01 * wx) * (1.f - wy) +
            (a10 * (1.f - wx) + a11 * wx) * wy;
  }
#pragma unroll
  for (int co = 0; co < 3; ++co) {
    float u = up_b[co];
#pragma unroll
    for (int ci = 0; ci < 3; ++ci) u = fmaf(up_w[co * 3 + ci], v[ci], u);
    const float sg = 1.0f / (1.0f + expf(-u));
    const size_t o = (((size_t)b * 3 + co) << 20) + ((size_t)oh << 10) + ow;
    outY[o] = sg * ctx[o];
  }
}

}  // namespace

extern "C" void kernel_launch(void* const* d_in, const int* in_sizes, int n_in,
                              void* d_out, int out_size, void* d_ws, size_t ws_size,
                              hipStream_t stream) {
  const float* img = (const float*)d_in[0];
  const float* ctx = (const float*)d_in[1];
  const float* patch_w = (const float*)d_in[2];
  const float* patch_b = (const float*)d_in[3];
  const float* pos1 = (const float*)d_in[4];
  const float* ctx_w = (const float*)d_in[5];
  const float* ctx_b = (const float*)d_in[6];
  const float* pos2 = (const float*)d_in[7];
  const float* qkv_w = (const float*)d_in[8];
  const float* proj_w = (const float*)d_in[9];
  const float* proj_b = (const float*)d_in[10];
  const float* up_w = (const float*)d_in[11];
  const float* up_b = (const float*)d_in[12];

  char* wsb = (char*)d_ws;
  u16* Pbf  = (u16*)(wsb);
  u16* Aimg = (u16*)(wsb);              // alias, dead before softmax
  u16* Actx = (u16*)(wsb + 12582912);
  u16* XC   = (u16*)(wsb + 25165824);
  u16* Qm   = (u16*)(wsb + 50331648);
  u16* Km   = (u16*)(wsb + 75497472);
  u16* Vt   = (u16*)(wsb + 134217728);
  u16* O2   = (u16*)(wsb + 159383552);
  float* P  = (float*)(wsb + 184549376);
  u16* Wpat = (u16*)(wsb + 209715200);
  u16* Wctx = (u16*)(wsb + 210894848);
  u16* Wqt  = (u16*)(wsb + 212074496);
  u16* Wpt  = (u16*)(wsb + 215613440);

  float* outY = (float*)d_out;             // (8,3,1024,1024)
  float* outA = (float*)d_out + 25165824;  // (8,8,1024,1024)

  cvt_bf16<<<576, 256, 0, stream>>>(patch_w, Wpat);
  cvt_bf16<<<576, 256, 0, stream>>>(ctx_w, Wctx);
  cvt_t<<<dim3(72, 24), dim3(32, 8), 0, stream>>>(qkv_w, Wqt, 2304, 768);
  cvt_t<<<dim3(12, 24), dim3(32, 8), 0, stream>>>(proj_w, Wpt, 384, 768);
  im2col_img<<<8192, 192, 0, stream>>>(img, Aimg);
  im2col_ctx<<<8192, 192, 0, stream>>>(ctx, Actx);
  patch_gemm<<<dim3(6, 64), 256, 0, stream>>>(Aimg, Wpat, patch_b, pos1, XC, 0);
  patch_gemm<<<dim3(6, 64), 256, 0, stream>>>(Actx, Wctx, ctx_b, pos2, XC, 1);
  qkv_gemm<<<dim3(18, 128), 256, 0, stream>>>(XC, Wqt, Qm, Km, Vt);
  qk_gemm<<<dim3(8, 8, 64), 256, 0, stream>>>(Qm, Km, outA);
  softmax_k<<<65536, 256, 0, stream>>>(outA, Pbf);
  pv_gemm<<<dim3(1, 8, 64), 256, 0, stream>>>(Pbf, Vt, O2);
  proj_gemm<<<dim3(3, 128), 256, 0, stream>>>(O2, Wpt, proj_b, P);
  final_up<<<32768, 256, 0, stream>>>(P, ctx, up_w, up_b, outY);
}